// Round 1
// baseline (801.029 us; speedup 1.0000x reference)
//
#include <hip/hip_runtime.h>
#include <hip/hip_bf16.h>

#define B_   64
#define N_   512
#define T_   8
#define DIN_ 2
#define H_   256
#define L_   3
#define E_   8192
#define M_   128
#define P2_  24   // P*2
#define EPS_ 1e-5f

#define TILE 64
#define KC   16

// -------------------- encoder: h[b,n,c] = mean_t relu(obs@Wenc + benc) ----
__global__ __launch_bounds__(256) void encoder_kernel(
    const float* __restrict__ obs, const float* __restrict__ Wenc,
    const float* __restrict__ benc, float* __restrict__ h)
{
    int bn = blockIdx.x;          // b*N + n
    int c  = threadIdx.x;         // channel
    __shared__ float o[T_ * DIN_];
    if (c < T_ * DIN_) o[c] = obs[(long)bn * T_ * DIN_ + c];
    __syncthreads();
    float w0 = Wenc[c], w1 = Wenc[H_ + c], bb = benc[c];
    float acc = 0.f;
#pragma unroll
    for (int t = 0; t < T_; ++t) {
        float v = o[2 * t] * w0 + o[2 * t + 1] * w1 + bb;
        acc += fmaxf(v, 0.f);
    }
    h[(long)bn * H_ + c] = acc * 0.125f;
}

// -------------------- densify incidence matrix + degrees ------------------
__global__ __launch_bounds__(256) void build_kernel(const int* __restrict__ idx,
    float* __restrict__ Hmat, float* __restrict__ HmatT,
    float* __restrict__ degN, float* __restrict__ degM)
{
    int b = blockIdx.x;
    const int* nodes = idx + (long)b * 2 * E_;
    const int* edges = nodes + E_;
    for (int e = threadIdx.x; e < E_; e += blockDim.x) {
        int n = nodes[e], m = edges[e];
        atomicAdd(&Hmat[((long)b * N_ + n) * M_ + m], 1.0f);
        atomicAdd(&HmatT[((long)b * M_ + m) * N_ + n], 1.0f);
        atomicAdd(&degN[b * N_ + n], 1.0f);
        atomicAdd(&degM[b * M_ + m], 1.0f);
    }
}

__global__ void inv_kernel(float* deg, int n) {
    int i = blockIdx.x * blockDim.x + threadIdx.x;
    if (i < n) deg[i] = 1.0f / fmaxf(deg[i], 1.0f);
}

// -------------------- generic batched GEMM ------------------------------
// C[b] = rowscale[b] * (A[b](+A2[b]) @ Bm[b]) + bias
// A: [M,K] row-major (lda=K), Bm: [K,Nn] (ldb=Nn), C: [M,Nn].
// Requires: M % 64 == 0, K % 16 == 0.  Nn arbitrary (guarded).
__global__ __launch_bounds__(256) void gemm_kernel(
    const float* __restrict__ A, const float* __restrict__ A2, long aStride,
    const float* __restrict__ Bm, long bStride,
    float* __restrict__ C, long cStride,
    int M, int Nn, int K,
    const float* __restrict__ rowscale, int rsStride,
    const float* __restrict__ bias)
{
    int b  = blockIdx.z;
    int m0 = blockIdx.y * TILE;
    int n0 = blockIdx.x * TILE;
    const float* Ab  = A + (long)b * aStride;
    const float* A2b = A2 ? A2 + (long)b * aStride : nullptr;
    const float* Bb  = Bm + (long)b * bStride;
    float*       Cb  = C + (long)b * cStride;

    __shared__ float As[KC][TILE];   // [k][m]
    __shared__ float Bs[KC][TILE];   // [k][n]

    int tid = threadIdx.x;
    int tx  = tid & 15;
    int ty  = tid >> 4;
    int tx4 = tx << 2;
    int ty4 = ty << 2;

    // loader indices
    int lr  = tid >> 2;           // 0..63 : A row within tile
    int lc4 = (tid & 3) << 2;     // 0,4,8,12 : A k-offset
    int br  = tid >> 4;           // 0..15 : B k-row
    int bc4 = (tid & 15) << 2;    // 0..60 : B col-offset

    float acc[4][4] = {};

    for (int k0 = 0; k0 < K; k0 += KC) {
        // A tile (M always multiple of 64 -> no row guard; K mult of 16)
        const float* ap = Ab + (long)(m0 + lr) * K + k0 + lc4;
        float4 av = *(const float4*)ap;
        if (A2b) {
            float4 a2 = *(const float4*)(A2b + (long)(m0 + lr) * K + k0 + lc4);
            av.x += a2.x; av.y += a2.y; av.z += a2.z; av.w += a2.w;
        }
        As[lc4 + 0][lr] = av.x;
        As[lc4 + 1][lr] = av.y;
        As[lc4 + 2][lr] = av.z;
        As[lc4 + 3][lr] = av.w;
        // B tile
        int cc = n0 + bc4;
        float4 bv = make_float4(0.f, 0.f, 0.f, 0.f);
        const float* bp = Bb + (long)(k0 + br) * Nn + cc;
        if (cc + 3 < Nn) {
            bv = *(const float4*)bp;
        } else {
            if (cc + 0 < Nn) bv.x = bp[0];
            if (cc + 1 < Nn) bv.y = bp[1];
            if (cc + 2 < Nn) bv.z = bp[2];
            if (cc + 3 < Nn) bv.w = bp[3];
        }
        *(float4*)&Bs[br][bc4] = bv;
        __syncthreads();
#pragma unroll
        for (int kk = 0; kk < KC; ++kk) {
            float4 a  = *(const float4*)&As[kk][ty4];
            float4 bq = *(const float4*)&Bs[kk][tx4];
            acc[0][0] += a.x * bq.x; acc[0][1] += a.x * bq.y;
            acc[0][2] += a.x * bq.z; acc[0][3] += a.x * bq.w;
            acc[1][0] += a.y * bq.x; acc[1][1] += a.y * bq.y;
            acc[1][2] += a.y * bq.z; acc[1][3] += a.y * bq.w;
            acc[2][0] += a.z * bq.x; acc[2][1] += a.z * bq.y;
            acc[2][2] += a.z * bq.z; acc[2][3] += a.z * bq.w;
            acc[3][0] += a.w * bq.x; acc[3][1] += a.w * bq.y;
            acc[3][2] += a.w * bq.z; acc[3][3] += a.w * bq.w;
        }
        __syncthreads();
    }

#pragma unroll
    for (int i = 0; i < 4; ++i) {
        int r = m0 + ty4 + i;
        float rs = rowscale ? rowscale[(long)b * rsStride + r] : 1.0f;
#pragma unroll
        for (int j = 0; j < 4; ++j) {
            int c = n0 + tx4 + j;
            if (c < Nn) {
                float v = acc[i][j] * rs;
                if (bias) v += bias[c];
                Cb[(long)r * Nn + c] = v;
            }
        }
    }
}

// -------------------- per-sample BatchNorm over node dim + ReLU -----------
__global__ __launch_bounds__(64) void bn_relu_kernel(const float* __restrict__ hc,
    float* __restrict__ hs, const float* __restrict__ gamma,
    const float* __restrict__ beta)
{
    int b = blockIdx.x;
    int c = blockIdx.y * 64 + threadIdx.x;
    const float* x = hc + (long)b * N_ * H_;
    float s = 0.f, s2 = 0.f;
#pragma unroll 8
    for (int n = 0; n < N_; ++n) {
        float v = x[n * H_ + c];
        s += v; s2 += v * v;
    }
    float mu  = s * (1.0f / N_);
    float var = s2 * (1.0f / N_) - mu * mu;
    float sc  = gamma[c] * rsqrtf(var + EPS_);
    float sh  = beta[c] - mu * sc;
    float* y = hs + (long)b * N_ * H_;
#pragma unroll 8
    for (int n = 0; n < N_; ++n) {
        y[n * H_ + c] = fmaxf(x[n * H_ + c] * sc + sh, 0.f);
    }
}

// --------------------------------------------------------------------------
extern "C" void kernel_launch(void* const* d_in, const int* in_sizes, int n_in,
                              void* d_out, int out_size, void* d_ws, size_t ws_size,
                              hipStream_t stream) {
    const float* obs    = (const float*)d_in[0];
    const int*   hyper  = (const int*)d_in[1];
    const float* Wenc   = (const float*)d_in[2];
    const float* benc   = (const float*)d_in[3];
    const float* thetas = (const float*)d_in[4];
    const float* convb  = (const float*)d_in[5];
    const float* gammas = (const float*)d_in[6];
    const float* betas  = (const float*)d_in[7];
    const float* Wdec   = (const float*)d_in[8];
    const float* bdec   = (const float*)d_in[9];
    float* out = (float*)d_out;
    float* ws  = (float*)d_ws;

    size_t o = 0;
    float* Hmat  = ws + o; o += (size_t)B_ * N_ * M_;
    float* HmatT = ws + o; o += (size_t)B_ * M_ * N_;
    float* degN  = ws + o; o += (size_t)B_ * N_;
    float* degM  = ws + o; o += (size_t)B_ * M_;
    size_t zeroBytes = o * sizeof(float);
    float* h   = ws + o; o += (size_t)B_ * N_ * H_;
    float* hs  = ws + o; o += (size_t)B_ * N_ * H_;
    float* xt  = ws + o; o += (size_t)B_ * N_ * H_;  // also reused as hc
    float* msg = ws + o; o += (size_t)B_ * M_ * H_;

    hipMemsetAsync(d_ws, 0, zeroBytes, stream);
    encoder_kernel<<<B_ * N_, 256, 0, stream>>>(obs, Wenc, benc, h);
    build_kernel<<<B_, 256, 0, stream>>>(hyper, Hmat, HmatT, degN, degM);
    inv_kernel<<<(B_ * (N_ + M_) + 255) / 256, 256, 0, stream>>>(degN, B_ * (N_ + M_));

    const float* cur = h;
    for (int l = 0; l < L_; ++l) {
        // xt = cur @ theta_l        [512,256] = [512,256]@[256,256]
        gemm_kernel<<<dim3(H_ / TILE, N_ / TILE, B_), 256, 0, stream>>>(
            cur, nullptr, (long)N_ * H_, thetas + (size_t)l * H_ * H_, 0,
            xt, (long)N_ * H_, N_, H_, H_, nullptr, 0, nullptr);
        // msg = invb * (HmatT @ xt) [128,256] = [128,512]@[512,256]
        gemm_kernel<<<dim3(H_ / TILE, M_ / TILE, B_), 256, 0, stream>>>(
            HmatT, nullptr, (long)M_ * N_, xt, (long)N_ * H_,
            msg, (long)M_ * H_, M_, H_, N_, degM, M_, nullptr);
        // hc = invd * (Hmat @ msg) + conv_bias  [512,256] = [512,128]@[128,256]
        gemm_kernel<<<dim3(H_ / TILE, N_ / TILE, B_), 256, 0, stream>>>(
            Hmat, nullptr, (long)N_ * M_, msg, (long)M_ * H_,
            xt, (long)N_ * H_, N_, H_, M_, degN, N_, convb + (size_t)l * H_);
        // BN (train-mode stats over node dim) + relu -> hs
        bn_relu_kernel<<<dim3(B_, H_ / 64), 64, 0, stream>>>(
            xt, hs, gammas + (size_t)l * H_, betas + (size_t)l * H_);
        cur = hs;
    }
    // out = (h + hs) @ Wdec + bdec   [512,24] = [512,256]@[256,24]
    gemm_kernel<<<dim3(1, N_ / TILE, B_), 256, 0, stream>>>(
        h, hs, (long)N_ * H_, Wdec, 0,
        out, (long)N_ * P2_, N_, P2_, H_, nullptr, 0, bdec);
}

// Round 3
// 508.159 us; speedup vs baseline: 1.5763x; 1.5763x over previous
//
#include <hip/hip_runtime.h>
#include <hip/hip_bf16.h>

#define B_   64
#define N_   512
#define T_   8
#define DIN_ 2
#define H_   256
#define L_   3
#define E_   8192
#define M_   128
#define P2_  24   // P*2
#define EPS_ 1e-5f

#define TILE 64
#define KC   16

typedef __attribute__((ext_vector_type(8))) short short8;
typedef __attribute__((ext_vector_type(4))) float floatx4;

__device__ __forceinline__ unsigned short f2bf(float f) {
    union { float f; unsigned u; } v; v.f = f;
    unsigned r = v.u + 0x7FFF + ((v.u >> 16) & 1);
    return (unsigned short)(r >> 16);
}
__device__ __forceinline__ float bf2f(unsigned short h) {
    union { unsigned u; float f; } v; v.u = (unsigned)h << 16; return v.f;
}

// -------------------- encoder: h[b,n,c] = mean_t relu(obs@Wenc + benc) ----
__global__ __launch_bounds__(256) void encoder_kernel(
    const float* __restrict__ obs, const float* __restrict__ Wenc,
    const float* __restrict__ benc, float* __restrict__ h)
{
    int bn = blockIdx.x;
    int c  = threadIdx.x;
    __shared__ float o[T_ * DIN_];
    if (c < T_ * DIN_) o[c] = obs[(long)bn * T_ * DIN_ + c];
    __syncthreads();
    float w0 = Wenc[c], w1 = Wenc[H_ + c], bb = benc[c];
    float acc = 0.f;
#pragma unroll
    for (int t = 0; t < T_; ++t) {
        float v = o[2 * t] * w0 + o[2 * t + 1] * w1 + bb;
        acc += fmaxf(v, 0.f);
    }
    h[(long)bn * H_ + c] = acc * 0.125f;
}

// -------------------- densify incidence via LDS counts --------------------
__global__ __launch_bounds__(256) void build_kernel(const int* __restrict__ idx,
    unsigned short* __restrict__ Hmat, unsigned short* __restrict__ HmatT,
    float* __restrict__ DinvN, float* __restrict__ degM)
{
    int b = blockIdx.x;
    int chunk = blockIdx.y;
    int c0 = chunk * 64;
    __shared__ unsigned int cnt[64 * 129];
    for (int i = threadIdx.x; i < 64 * 129; i += 256) cnt[i] = 0;
    __syncthreads();
    const int* nodes = idx + (long)b * 2 * E_;
    const int* edges = nodes + E_;
    for (int e = threadIdx.x; e < E_; e += 256) {
        int n = nodes[e];
        if ((n >> 6) == chunk) {
            int m = edges[e];
            atomicAdd(&cnt[(n & 63) * 129 + m], 1u);
        }
    }
    __syncthreads();
    for (int i = threadIdx.x; i < 64 * 128; i += 256) {
        int r = i >> 7, m = i & 127;
        Hmat[((long)(b * N_ + c0 + r)) * M_ + m] = f2bf((float)cnt[r * 129 + m]);
    }
    for (int i = threadIdx.x; i < 64 * 128; i += 256) {
        int m = i >> 6, r = i & 63;
        HmatT[((long)(b * M_ + m)) * N_ + c0 + r] = f2bf((float)cnt[r * 129 + m]);
    }
    if (threadIdx.x < 64) {
        int r = threadIdx.x;
        unsigned s = 0;
#pragma unroll 8
        for (int m = 0; m < 128; ++m) s += cnt[r * 129 + m];
        DinvN[b * N_ + c0 + r] = 1.0f / fmaxf((float)s, 1.0f);
    } else if (threadIdx.x < 192) {
        int m = threadIdx.x - 64;
        unsigned s = 0;
#pragma unroll 8
        for (int r = 0; r < 64; ++r) s += cnt[r * 129 + m];
        atomicAdd(&degM[b * M_ + m], (float)s);
    }
}

__global__ void inv_kernel(float* deg, int n) {
    int i = blockIdx.x * blockDim.x + threadIdx.x;
    if (i < n) deg[i] = 1.0f / fmaxf(deg[i], 1.0f);
}

// ---------- fp32 [R,C] -> SPLIT bf16 [C,R] batched transpose --------------
__global__ __launch_bounds__(256) void transpose_f32_bf16split(
    const float* __restrict__ in, long inStride,
    unsigned short* __restrict__ outT, long outStride, long loOff, int R, int C)
{
    int b = blockIdx.z;
    int r0 = blockIdx.y * 64, c0 = blockIdx.x * 64;
    __shared__ float tile[64][65];
    const float* ib = in + (long)b * inStride;
    unsigned short* ob = outT + (long)b * outStride;
    int x = threadIdx.x & 63;
    int y0 = threadIdx.x >> 6;
#pragma unroll
    for (int i = 0; i < 16; ++i) {
        int y = y0 * 16 + i;
        tile[y][x] = ib[(long)(r0 + y) * C + c0 + x];
    }
    __syncthreads();
#pragma unroll
    for (int i = 0; i < 16; ++i) {
        int y = y0 * 16 + i;
        float v = tile[x][y];
        unsigned short hv = f2bf(v);
        long idx = (long)(c0 + y) * R + r0 + x;
        ob[idx] = hv;
        ob[loOff + idx] = f2bf(v - bf2f(hv));
    }
}

// -------------------- split-bf16 MFMA GEMM --------------------------------
// C = rowscale * (A @ B) + bias.  A: [M,K] bf16 row-major; BT: [Nn,K] bf16.
// ASPLIT/BSPLIT: operand has a lo-correction plane at +{a,b}LoOff elements.
// OUT_SPLIT: write hi/lo bf16 pair (lo at +cLoOff), else fp32.
template <int WM, int WN, bool ASPLIT, bool BSPLIT, bool OUT_SPLIT>
__global__ __launch_bounds__(WM * WN * 64) void mfma_gemm(
    const unsigned short* __restrict__ A, long aStride, long aLoOff,
    const unsigned short* __restrict__ BT, long btStride, long bLoOff,
    void* __restrict__ Cout, long cStride, long cLoOff,
    int M, int Nn, int K,
    const float* __restrict__ rowscale, int rsStride,
    const float* __restrict__ bias)
{
    constexpr int BM = WM * 64, BN = WN * 64, NT = WM * WN * 64;
    int b  = blockIdx.z;
    int m0 = blockIdx.y * BM;
    int n0 = blockIdx.x * BN;
    const unsigned short* Ag = A + (long)b * aStride + (long)m0 * K;
    const unsigned short* Bg = BT + (long)b * btStride + (long)n0 * K;

    __shared__ __align__(16) unsigned short As[BM * 40];
    __shared__ __align__(16) unsigned short AsLo[ASPLIT ? BM * 40 : 16];
    __shared__ __align__(16) unsigned short Bs[BN * 40];
    __shared__ __align__(16) unsigned short BsLo[BSPLIT ? BN * 40 : 16];

    int tid  = threadIdx.x;
    int wave = tid >> 6, lane = tid & 63;
    int wm = (wave / WN) * 64, wn = (wave % WN) * 64;
    int lr = lane & 15, lq = lane >> 4;

    floatx4 acc[4][4] = {};

    for (int k0 = 0; k0 < K; k0 += 32) {
#pragma unroll
        for (int i = tid; i < BM * 4; i += NT) {
            int r = i >> 2, ck = (i & 3) << 3;
            *(uint4*)&As[r * 40 + ck] = *(const uint4*)&Ag[(long)r * K + k0 + ck];
            if (ASPLIT)
                *(uint4*)&AsLo[r * 40 + ck] = *(const uint4*)&Ag[aLoOff + (long)r * K + k0 + ck];
        }
#pragma unroll
        for (int i = tid; i < BN * 4; i += NT) {
            int r = i >> 2, ck = (i & 3) << 3;
            *(uint4*)&Bs[r * 40 + ck] = *(const uint4*)&Bg[(long)r * K + k0 + ck];
            if (BSPLIT)
                *(uint4*)&BsLo[r * 40 + ck] = *(const uint4*)&Bg[bLoOff + (long)r * K + k0 + ck];
        }
        __syncthreads();
        short8 ah[4], bh[4], al[4], bl[4];
#pragma unroll
        for (int mt = 0; mt < 4; ++mt) {
            ah[mt] = *(const short8*)&As[(wm + mt * 16 + lr) * 40 + lq * 8];
            if (ASPLIT) al[mt] = *(const short8*)&AsLo[(wm + mt * 16 + lr) * 40 + lq * 8];
        }
#pragma unroll
        for (int nt = 0; nt < 4; ++nt) {
            bh[nt] = *(const short8*)&Bs[(wn + nt * 16 + lr) * 40 + lq * 8];
            if (BSPLIT) bl[nt] = *(const short8*)&BsLo[(wn + nt * 16 + lr) * 40 + lq * 8];
        }
#pragma unroll
        for (int mt = 0; mt < 4; ++mt)
#pragma unroll
            for (int nt = 0; nt < 4; ++nt) {
                acc[mt][nt] = __builtin_amdgcn_mfma_f32_16x16x32_bf16(
                    ah[mt], bh[nt], acc[mt][nt], 0, 0, 0);
                if (BSPLIT)
                    acc[mt][nt] = __builtin_amdgcn_mfma_f32_16x16x32_bf16(
                        ah[mt], bl[nt], acc[mt][nt], 0, 0, 0);
                if (ASPLIT)
                    acc[mt][nt] = __builtin_amdgcn_mfma_f32_16x16x32_bf16(
                        al[mt], bh[nt], acc[mt][nt], 0, 0, 0);
            }
        __syncthreads();
    }

    // epilogue: C/D layout col=lane&15, row=(lane>>4)*4+reg
    float rs[4][4];
#pragma unroll
    for (int mt = 0; mt < 4; ++mt)
#pragma unroll
        for (int r4 = 0; r4 < 4; ++r4)
            rs[mt][r4] = rowscale
                ? rowscale[(long)b * rsStride + m0 + wm + mt * 16 + lq * 4 + r4]
                : 1.0f;
    float bi[4];
#pragma unroll
    for (int nt = 0; nt < 4; ++nt)
        bi[nt] = bias ? bias[n0 + wn + nt * 16 + lr] : 0.0f;

#pragma unroll
    for (int mt = 0; mt < 4; ++mt) {
#pragma unroll
        for (int nt = 0; nt < 4; ++nt) {
            long col = n0 + wn + nt * 16 + lr;
#pragma unroll
            for (int r4 = 0; r4 < 4; ++r4) {
                long row = m0 + wm + mt * 16 + lq * 4 + r4;
                float v = acc[mt][nt][r4] * rs[mt][r4] + bi[nt];
                long idx = (long)b * cStride + row * Nn + col;
                if (OUT_SPLIT) {
                    unsigned short hv = f2bf(v);
                    ((unsigned short*)Cout)[idx] = hv;
                    ((unsigned short*)Cout)[cLoOff + idx] = f2bf(v - bf2f(hv));
                } else {
                    ((float*)Cout)[idx] = v;
                }
            }
        }
    }
}

// -------------------- per-sample BatchNorm over node dim + ReLU -----------
__global__ __launch_bounds__(64) void bn_relu_kernel(const float* __restrict__ hc,
    float* __restrict__ hs, const float* __restrict__ gamma,
    const float* __restrict__ beta)
{
    int b = blockIdx.x;
    int c = blockIdx.y * 64 + threadIdx.x;
    const float* x = hc + (long)b * N_ * H_;
    float s = 0.f, s2 = 0.f;
#pragma unroll 8
    for (int n = 0; n < N_; ++n) {
        float v = x[n * H_ + c];
        s += v; s2 += v * v;
    }
    float mu  = s * (1.0f / N_);
    float var = s2 * (1.0f / N_) - mu * mu;
    float sc  = gamma[c] * rsqrtf(var + EPS_);
    float sh  = beta[c] - mu * sc;
    float* y = hs + (long)b * N_ * H_;
#pragma unroll 8
    for (int n = 0; n < N_; ++n) {
        y[n * H_ + c] = fmaxf(x[n * H_ + c] * sc + sh, 0.f);
    }
}

// -------------------- fp32 tiled GEMM (decoder only) ----------------------
__global__ __launch_bounds__(256) void gemm_kernel(
    const float* __restrict__ A, const float* __restrict__ A2, long aStride,
    const float* __restrict__ Bm, long bStride,
    float* __restrict__ C, long cStride,
    int M, int Nn, int K,
    const float* __restrict__ rowscale, int rsStride,
    const float* __restrict__ bias)
{
    int b  = blockIdx.z;
    int m0 = blockIdx.y * TILE;
    int n0 = blockIdx.x * TILE;
    const float* Ab  = A + (long)b * aStride;
    const float* A2b = A2 ? A2 + (long)b * aStride : nullptr;
    const float* Bb  = Bm + (long)b * bStride;
    float*       Cb  = C + (long)b * cStride;

    __shared__ float As[KC][TILE];
    __shared__ float Bs[KC][TILE];

    int tid = threadIdx.x;
    int tx  = tid & 15;
    int ty  = tid >> 4;
    int tx4 = tx << 2;
    int ty4 = ty << 2;
    int lr  = tid >> 2;
    int lc4 = (tid & 3) << 2;
    int br  = tid >> 4;
    int bc4 = (tid & 15) << 2;

    float acc[4][4] = {};

    for (int k0 = 0; k0 < K; k0 += KC) {
        const float* ap = Ab + (long)(m0 + lr) * K + k0 + lc4;
        float4 av = *(const float4*)ap;
        if (A2b) {
            float4 a2 = *(const float4*)(A2b + (long)(m0 + lr) * K + k0 + lc4);
            av.x += a2.x; av.y += a2.y; av.z += a2.z; av.w += a2.w;
        }
        As[lc4 + 0][lr] = av.x;
        As[lc4 + 1][lr] = av.y;
        As[lc4 + 2][lr] = av.z;
        As[lc4 + 3][lr] = av.w;
        int cc = n0 + bc4;
        float4 bv = make_float4(0.f, 0.f, 0.f, 0.f);
        const float* bp = Bb + (long)(k0 + br) * Nn + cc;
        if (cc + 3 < Nn) {
            bv = *(const float4*)bp;
        } else {
            if (cc + 0 < Nn) bv.x = bp[0];
            if (cc + 1 < Nn) bv.y = bp[1];
            if (cc + 2 < Nn) bv.z = bp[2];
            if (cc + 3 < Nn) bv.w = bp[3];
        }
        *(float4*)&Bs[br][bc4] = bv;
        __syncthreads();
#pragma unroll
        for (int kk = 0; kk < KC; ++kk) {
            float4 a  = *(const float4*)&As[kk][ty4];
            float4 bq = *(const float4*)&Bs[kk][tx4];
            acc[0][0] += a.x * bq.x; acc[0][1] += a.x * bq.y;
            acc[0][2] += a.x * bq.z; acc[0][3] += a.x * bq.w;
            acc[1][0] += a.y * bq.x; acc[1][1] += a.y * bq.y;
            acc[1][2] += a.y * bq.z; acc[1][3] += a.y * bq.w;
            acc[2][0] += a.z * bq.x; acc[2][1] += a.z * bq.y;
            acc[2][2] += a.z * bq.z; acc[2][3] += a.z * bq.w;
            acc[3][0] += a.w * bq.x; acc[3][1] += a.w * bq.y;
            acc[3][2] += a.w * bq.z; acc[3][3] += a.w * bq.w;
        }
        __syncthreads();
    }

#pragma unroll
    for (int i = 0; i < 4; ++i) {
        int r = m0 + ty4 + i;
        float rsv = rowscale ? rowscale[(long)b * rsStride + r] : 1.0f;
#pragma unroll
        for (int j = 0; j < 4; ++j) {
            int c = n0 + tx4 + j;
            if (c < Nn) {
                float v = acc[i][j] * rsv;
                if (bias) v += bias[c];
                Cb[(long)r * Nn + c] = v;
            }
        }
    }
}

// --------------------------------------------------------------------------
extern "C" void kernel_launch(void* const* d_in, const int* in_sizes, int n_in,
                              void* d_out, int out_size, void* d_ws, size_t ws_size,
                              hipStream_t stream) {
    const float* obs    = (const float*)d_in[0];
    const int*   hyper  = (const int*)d_in[1];
    const float* Wenc   = (const float*)d_in[2];
    const float* benc   = (const float*)d_in[3];
    const float* thetas = (const float*)d_in[4];
    const float* convb  = (const float*)d_in[5];
    const float* gammas = (const float*)d_in[6];
    const float* betas  = (const float*)d_in[7];
    const float* Wdec   = (const float*)d_in[8];
    const float* bdec   = (const float*)d_in[9];
    float* out = (float*)d_out;

    char* w = (char*)d_ws;
    auto alloc = [&](size_t bytes) { char* p = w; w += (bytes + 255) & ~255ULL; return p; };
    float* h     = (float*)alloc((size_t)B_ * N_ * H_ * 4);
    float* hs    = (float*)alloc((size_t)B_ * N_ * H_ * 4);
    float* DinvN = (float*)alloc((size_t)B_ * N_ * 4);
    float* BinvM = (float*)alloc((size_t)B_ * M_ * 4);
    unsigned short* Hmat  = (unsigned short*)alloc((size_t)B_ * N_ * M_ * 2);
    unsigned short* HmatT = (unsigned short*)alloc((size_t)B_ * M_ * N_ * 2);
    unsigned short* actT  = (unsigned short*)alloc((size_t)B_ * H_ * N_ * 2 * 2); // hi+lo
    unsigned short* Z     = (unsigned short*)alloc((size_t)B_ * M_ * H_ * 2 * 2);
    unsigned short* WtT   = (unsigned short*)alloc((size_t)B_ * H_ * M_ * 2 * 2);
    unsigned short* thT   = (unsigned short*)alloc((size_t)L_ * H_ * H_ * 2 * 2);

    const long actLo = (long)B_ * H_ * N_;
    const long zLo   = (long)B_ * M_ * H_;
    const long wtLo  = (long)B_ * H_ * M_;
    const long thLo  = (long)L_ * H_ * H_;

    hipMemsetAsync(BinvM, 0, (size_t)B_ * M_ * 4, stream);
    encoder_kernel<<<B_ * N_, 256, 0, stream>>>(obs, Wenc, benc, h);
    build_kernel<<<dim3(B_, 8), 256, 0, stream>>>(hyper, Hmat, HmatT, DinvN, BinvM);
    inv_kernel<<<(B_ * M_ + 255) / 256, 256, 0, stream>>>(BinvM, B_ * M_);
    // thetaT split bf16 once: [L][H,H] -> transposed per l
    transpose_f32_bf16split<<<dim3(4, 4, 3), 256, 0, stream>>>(
        thetas, (long)H_ * H_, thT, (long)H_ * H_, thLo, H_, H_);
    // actT = h^T split bf16
    transpose_f32_bf16split<<<dim3(4, 8, B_), 256, 0, stream>>>(
        h, (long)N_ * H_, actT, (long)H_ * N_, actLo, N_, H_);

    for (int l = 0; l < L_; ++l) {
        // Z = Binv * (HmatT @ act)  [128,256], K=512 ; A exact, B split
        mfma_gemm<1, 2, false, true, true><<<dim3(2, 2, B_), 128, 0, stream>>>(
            HmatT, (long)M_ * N_, 0, actT, (long)H_ * N_, actLo,
            Z, (long)M_ * H_, zLo, M_, H_, N_, BinvM, M_, nullptr);
        // WtT = thetaT_l @ Z^T  [256,128], K=256 ; both split
        mfma_gemm<1, 2, true, true, true><<<dim3(1, 4, B_), 128, 0, stream>>>(
            thT + (size_t)l * H_ * H_, 0, thLo, Z, (long)M_ * H_, zLo,
            WtT, (long)H_ * M_, wtLo, H_, M_, H_, nullptr, 0, nullptr);
        // hc = Dinv * (Hmat @ Wt) + convb  [512,256] fp32 ; A exact, B split
        mfma_gemm<2, 2, false, true, false><<<dim3(2, 4, B_), 256, 0, stream>>>(
            Hmat, (long)N_ * M_, 0, WtT, (long)H_ * M_, wtLo,
            hs, (long)N_ * H_, 0, N_, H_, M_, DinvN, N_, convb + (size_t)l * H_);
        // BN + ReLU in place
        bn_relu_kernel<<<dim3(B_, H_ / 64), 64, 0, stream>>>(
            hs, hs, gammas + (size_t)l * H_, betas + (size_t)l * H_);
        // actT = hs^T split bf16
        transpose_f32_bf16split<<<dim3(4, 8, B_), 256, 0, stream>>>(
            hs, (long)N_ * H_, actT, (long)H_ * N_, actLo, N_, H_);
    }
    // out = (h + hs) @ Wdec + bdec (fp32)
    gemm_kernel<<<dim3(1, N_ / TILE, B_), 256, 0, stream>>>(
        h, hs, (long)N_ * H_, Wdec, 0,
        out, (long)N_ * P2_, N_, P2_, H_, nullptr, 0, bdec);
}

// Round 4
// 399.122 us; speedup vs baseline: 2.0070x; 1.2732x over previous
//
#include <hip/hip_runtime.h>
#include <hip/hip_bf16.h>

#define B_   64
#define N_   512
#define T_   8
#define DIN_ 2
#define H_   256
#define L_   3
#define E_   8192
#define M_   128
#define P2_  24   // P*2
#define EPS_ 1e-5f

#define TILE 64
#define KC   16

typedef __attribute__((ext_vector_type(8))) short short8;
typedef __attribute__((ext_vector_type(4))) float floatx4;

__device__ __forceinline__ unsigned short f2bf(float f) {
    union { float f; unsigned u; } v; v.f = f;
    unsigned r = v.u + 0x7FFF + ((v.u >> 16) & 1);
    return (unsigned short)(r >> 16);
}
__device__ __forceinline__ float bf2f(unsigned short h) {
    union { unsigned u; float f; } v; v.u = (unsigned)h << 16; return v.f;
}

// -------------------- encoder: h[b,n,c] = mean_t relu(obs@Wenc + benc) ----
__global__ __launch_bounds__(256) void encoder_kernel(
    const float* __restrict__ obs, const float* __restrict__ Wenc,
    const float* __restrict__ benc, float* __restrict__ h)
{
    int bn = blockIdx.x;
    int c  = threadIdx.x;
    __shared__ float o[T_ * DIN_];
    if (c < T_ * DIN_) o[c] = obs[(long)bn * T_ * DIN_ + c];
    __syncthreads();
    float w0 = Wenc[c], w1 = Wenc[H_ + c], bb = benc[c];
    float acc = 0.f;
#pragma unroll
    for (int t = 0; t < T_; ++t) {
        float v = o[2 * t] * w0 + o[2 * t + 1] * w1 + bb;
        acc += fmaxf(v, 0.f);
    }
    h[(long)bn * H_ + c] = acc * 0.125f;
}

// -------------------- densify incidence via LDS counts --------------------
__global__ __launch_bounds__(256) void build_kernel(const int* __restrict__ idx,
    unsigned short* __restrict__ Hmat, unsigned short* __restrict__ HmatT,
    float* __restrict__ DinvN, float* __restrict__ degM)
{
    int b = blockIdx.x;
    int chunk = blockIdx.y;
    int c0 = chunk * 64;
    __shared__ unsigned int cnt[64 * 129];
    for (int i = threadIdx.x; i < 64 * 129; i += 256) cnt[i] = 0;
    __syncthreads();
    const int* nodes = idx + (long)b * 2 * E_;
    const int* edges = nodes + E_;
    for (int e = threadIdx.x; e < E_; e += 256) {
        int n = nodes[e];
        if ((n >> 6) == chunk) {
            int m = edges[e];
            atomicAdd(&cnt[(n & 63) * 129 + m], 1u);
        }
    }
    __syncthreads();
    for (int i = threadIdx.x; i < 64 * 128; i += 256) {
        int r = i >> 7, m = i & 127;
        Hmat[((long)(b * N_ + c0 + r)) * M_ + m] = f2bf((float)cnt[r * 129 + m]);
    }
    for (int i = threadIdx.x; i < 64 * 128; i += 256) {
        int m = i >> 6, r = i & 63;
        HmatT[((long)(b * M_ + m)) * N_ + c0 + r] = f2bf((float)cnt[r * 129 + m]);
    }
    if (threadIdx.x < 64) {
        int r = threadIdx.x;
        unsigned s = 0;
#pragma unroll 8
        for (int m = 0; m < 128; ++m) s += cnt[r * 129 + m];
        DinvN[b * N_ + c0 + r] = 1.0f / fmaxf((float)s, 1.0f);
    } else if (threadIdx.x < 192) {
        int m = threadIdx.x - 64;
        unsigned s = 0;
#pragma unroll 8
        for (int r = 0; r < 64; ++r) s += cnt[r * 129 + m];
        atomicAdd(&degM[b * M_ + m], (float)s);
    }
}

__global__ void inv_kernel(float* deg, int n) {
    int i = blockIdx.x * blockDim.x + threadIdx.x;
    if (i < n) deg[i] = 1.0f / fmaxf(deg[i], 1.0f);
}

// ---------- fp32 [R,C] -> SPLIT bf16 [C,R] batched transpose --------------
__global__ __launch_bounds__(256) void transpose_f32_bf16split(
    const float* __restrict__ in, long inStride,
    unsigned short* __restrict__ outT, long outStride, long loOff, int R, int C)
{
    int b = blockIdx.z;
    int r0 = blockIdx.y * 64, c0 = blockIdx.x * 64;
    __shared__ float tile[64][65];
    const float* ib = in + (long)b * inStride;
    unsigned short* ob = outT + (long)b * outStride;
    int x = threadIdx.x & 63;
    int y0 = threadIdx.x >> 6;
#pragma unroll
    for (int i = 0; i < 16; ++i) {
        int y = y0 * 16 + i;
        tile[y][x] = ib[(long)(r0 + y) * C + c0 + x];
    }
    __syncthreads();
#pragma unroll
    for (int i = 0; i < 16; ++i) {
        int y = y0 * 16 + i;
        float v = tile[x][y];
        unsigned short hv = f2bf(v);
        long idx = (long)(c0 + y) * R + r0 + x;
        ob[idx] = hv;
        ob[loOff + idx] = f2bf(v - bf2f(hv));
    }
}

// -------------------- split-bf16 MFMA GEMM (gemm1 / gemm2) ----------------
// C = rowscale * (A @ B) + bias.  A: [M,K] bf16 row-major; BT: [Nn,K] bf16.
template <int WM, int WN, bool ASPLIT, bool BSPLIT, bool OUT_SPLIT>
__global__ __launch_bounds__(WM * WN * 64) void mfma_gemm(
    const unsigned short* __restrict__ A, long aStride, long aLoOff,
    const unsigned short* __restrict__ BT, long btStride, long bLoOff,
    void* __restrict__ Cout, long cStride, long cLoOff,
    int M, int Nn, int K,
    const float* __restrict__ rowscale, int rsStride,
    const float* __restrict__ bias)
{
    constexpr int BM = WM * 64, BN = WN * 64, NT = WM * WN * 64;
    int b  = blockIdx.z;
    int m0 = blockIdx.y * BM;
    int n0 = blockIdx.x * BN;
    const unsigned short* Ag = A + (long)b * aStride + (long)m0 * K;
    const unsigned short* Bg = BT + (long)b * btStride + (long)n0 * K;

    __shared__ __align__(16) unsigned short As[BM * 40];
    __shared__ __align__(16) unsigned short AsLo[ASPLIT ? BM * 40 : 16];
    __shared__ __align__(16) unsigned short Bs[BN * 40];
    __shared__ __align__(16) unsigned short BsLo[BSPLIT ? BN * 40 : 16];

    int tid  = threadIdx.x;
    int wave = tid >> 6, lane = tid & 63;
    int wm = (wave / WN) * 64, wn = (wave % WN) * 64;
    int lr = lane & 15, lq = lane >> 4;

    floatx4 acc[4][4] = {};

    for (int k0 = 0; k0 < K; k0 += 32) {
#pragma unroll
        for (int i = tid; i < BM * 4; i += NT) {
            int r = i >> 2, ck = (i & 3) << 3;
            *(uint4*)&As[r * 40 + ck] = *(const uint4*)&Ag[(long)r * K + k0 + ck];
            if (ASPLIT)
                *(uint4*)&AsLo[r * 40 + ck] = *(const uint4*)&Ag[aLoOff + (long)r * K + k0 + ck];
        }
#pragma unroll
        for (int i = tid; i < BN * 4; i += NT) {
            int r = i >> 2, ck = (i & 3) << 3;
            *(uint4*)&Bs[r * 40 + ck] = *(const uint4*)&Bg[(long)r * K + k0 + ck];
            if (BSPLIT)
                *(uint4*)&BsLo[r * 40 + ck] = *(const uint4*)&Bg[bLoOff + (long)r * K + k0 + ck];
        }
        __syncthreads();
        short8 ah[4], bh[4], al[4], bl[4];
#pragma unroll
        for (int mt = 0; mt < 4; ++mt) {
            ah[mt] = *(const short8*)&As[(wm + mt * 16 + lr) * 40 + lq * 8];
            if (ASPLIT) al[mt] = *(const short8*)&AsLo[(wm + mt * 16 + lr) * 40 + lq * 8];
        }
#pragma unroll
        for (int nt = 0; nt < 4; ++nt) {
            bh[nt] = *(const short8*)&Bs[(wn + nt * 16 + lr) * 40 + lq * 8];
            if (BSPLIT) bl[nt] = *(const short8*)&BsLo[(wn + nt * 16 + lr) * 40 + lq * 8];
        }
#pragma unroll
        for (int mt = 0; mt < 4; ++mt)
#pragma unroll
            for (int nt = 0; nt < 4; ++nt) {
                acc[mt][nt] = __builtin_amdgcn_mfma_f32_16x16x32_bf16(
                    ah[mt], bh[nt], acc[mt][nt], 0, 0, 0);
                if (BSPLIT)
                    acc[mt][nt] = __builtin_amdgcn_mfma_f32_16x16x32_bf16(
                        ah[mt], bl[nt], acc[mt][nt], 0, 0, 0);
                if (ASPLIT)
                    acc[mt][nt] = __builtin_amdgcn_mfma_f32_16x16x32_bf16(
                        al[mt], bh[nt], acc[mt][nt], 0, 0, 0);
            }
        __syncthreads();
    }

    float rs[4][4];
#pragma unroll
    for (int mt = 0; mt < 4; ++mt)
#pragma unroll
        for (int r4 = 0; r4 < 4; ++r4)
            rs[mt][r4] = rowscale
                ? rowscale[(long)b * rsStride + m0 + wm + mt * 16 + lq * 4 + r4]
                : 1.0f;
    float bi[4];
#pragma unroll
    for (int nt = 0; nt < 4; ++nt)
        bi[nt] = bias ? bias[n0 + wn + nt * 16 + lr] : 0.0f;

#pragma unroll
    for (int mt = 0; mt < 4; ++mt) {
#pragma unroll
        for (int nt = 0; nt < 4; ++nt) {
            long col = n0 + wn + nt * 16 + lr;
#pragma unroll
            for (int r4 = 0; r4 < 4; ++r4) {
                long row = m0 + wm + mt * 16 + lq * 4 + r4;
                float v = acc[mt][nt][r4] * rs[mt][r4] + bi[nt];
                long idx = (long)b * cStride + row * Nn + col;
                if (OUT_SPLIT) {
                    unsigned short hv = f2bf(v);
                    ((unsigned short*)Cout)[idx] = hv;
                    ((unsigned short*)Cout)[cLoOff + idx] = f2bf(v - bf2f(hv));
                } else {
                    ((float*)Cout)[idx] = v;
                }
            }
        }
    }
}

// ---- fused GEMM3 (transposed) + BatchNorm + ReLU + split-bf16 write ------
// hcT[h,n] = Dinv[n] * sum_m WtT[h][m] * Hmat[n][m] + convb[h]   (per batch)
// then per-row (h) BN over n=0..511, ReLU, write actT hi/lo [H,N].
// Block: 512 thr = 8 waves; wave w covers cols w*64..w*64+63, rows h0..h0+63.
__global__ __launch_bounds__(512) void gemm3_bn_kernel(
    const unsigned short* __restrict__ WtT, long wtStride, long wtLo,
    const unsigned short* __restrict__ Hmat, long hmStride,
    const float* __restrict__ DinvN,
    const float* __restrict__ convb,
    const float* __restrict__ gamma, const float* __restrict__ beta,
    unsigned short* __restrict__ actT, long actStride, long actLo)
{
    int b  = blockIdx.z;
    int h0 = blockIdx.y * 64;
    const unsigned short* Ag = WtT + (long)b * wtStride + (long)h0 * M_;
    const unsigned short* Bg = Hmat + (long)b * hmStride;

    __shared__ __align__(16) unsigned short As[64 * 40];
    __shared__ __align__(16) unsigned short AsLo[64 * 40];
    __shared__ __align__(16) unsigned short Bs[512 * 40];
    __shared__ float rsum[64][8];
    __shared__ float rsq[64][8];
    __shared__ float2 prm[64];

    int tid  = threadIdx.x;
    int wave = tid >> 6, lane = tid & 63;
    int wn = wave * 64;
    int lr = lane & 15, lq = lane >> 4;

    floatx4 acc[4][4] = {};

    for (int k0 = 0; k0 < M_; k0 += 32) {
#pragma unroll
        for (int i = tid; i < 64 * 4; i += 512) {
            int r = i >> 2, ck = (i & 3) << 3;
            *(uint4*)&As[r * 40 + ck]   = *(const uint4*)&Ag[(long)r * M_ + k0 + ck];
            *(uint4*)&AsLo[r * 40 + ck] = *(const uint4*)&Ag[wtLo + (long)r * M_ + k0 + ck];
        }
#pragma unroll
        for (int i = tid; i < 512 * 4; i += 512) {
            int r = i >> 2, ck = (i & 3) << 3;
            *(uint4*)&Bs[r * 40 + ck] = *(const uint4*)&Bg[(long)r * M_ + k0 + ck];
        }
        __syncthreads();
        short8 ah[4], al[4], bh[4];
#pragma unroll
        for (int mt = 0; mt < 4; ++mt) {
            ah[mt] = *(const short8*)&As[(mt * 16 + lr) * 40 + lq * 8];
            al[mt] = *(const short8*)&AsLo[(mt * 16 + lr) * 40 + lq * 8];
        }
#pragma unroll
        for (int nt = 0; nt < 4; ++nt)
            bh[nt] = *(const short8*)&Bs[(wn + nt * 16 + lr) * 40 + lq * 8];
#pragma unroll
        for (int mt = 0; mt < 4; ++mt)
#pragma unroll
            for (int nt = 0; nt < 4; ++nt) {
                acc[mt][nt] = __builtin_amdgcn_mfma_f32_16x16x32_bf16(
                    ah[mt], bh[nt], acc[mt][nt], 0, 0, 0);
                acc[mt][nt] = __builtin_amdgcn_mfma_f32_16x16x32_bf16(
                    al[mt], bh[nt], acc[mt][nt], 0, 0, 0);
            }
        __syncthreads();
    }

    // colscale (Dinv over n) + rowbias (convb over h)
    float dv[4];
#pragma unroll
    for (int nt = 0; nt < 4; ++nt)
        dv[nt] = DinvN[b * N_ + wn + nt * 16 + lr];
    float cb[4][4];
#pragma unroll
    for (int mt = 0; mt < 4; ++mt)
#pragma unroll
        for (int r4 = 0; r4 < 4; ++r4)
            cb[mt][r4] = convb[h0 + mt * 16 + lq * 4 + r4];
#pragma unroll
    for (int mt = 0; mt < 4; ++mt)
#pragma unroll
        for (int nt = 0; nt < 4; ++nt)
#pragma unroll
            for (int r4 = 0; r4 < 4; ++r4)
                acc[mt][nt][r4] = acc[mt][nt][r4] * dv[nt] + cb[mt][r4];

    // BN stats: per-lane partials over this lane's 4 cols (nt), then
    // shuffle-reduce over the 16 lr lanes, then LDS across 8 waves.
    float ps[4][4], pq[4][4];
#pragma unroll
    for (int mt = 0; mt < 4; ++mt)
#pragma unroll
        for (int r4 = 0; r4 < 4; ++r4) {
            float s = 0.f, q = 0.f;
#pragma unroll
            for (int nt = 0; nt < 4; ++nt) {
                float v = acc[mt][nt][r4];
                s += v; q += v * v;
            }
            ps[mt][r4] = s; pq[mt][r4] = q;
        }
#pragma unroll
    for (int mask = 1; mask <= 8; mask <<= 1) {
#pragma unroll
        for (int mt = 0; mt < 4; ++mt)
#pragma unroll
            for (int r4 = 0; r4 < 4; ++r4) {
                ps[mt][r4] += __shfl_xor(ps[mt][r4], mask);
                pq[mt][r4] += __shfl_xor(pq[mt][r4], mask);
            }
    }
    if (lr == 0) {
#pragma unroll
        for (int mt = 0; mt < 4; ++mt)
#pragma unroll
            for (int r4 = 0; r4 < 4; ++r4) {
                int row = mt * 16 + lq * 4 + r4;
                rsum[row][wave] = ps[mt][r4];
                rsq[row][wave]  = pq[mt][r4];
            }
    }
    __syncthreads();
    if (tid < 64) {
        float s = 0.f, s2 = 0.f;
#pragma unroll
        for (int w = 0; w < 8; ++w) { s += rsum[tid][w]; s2 += rsq[tid][w]; }
        float mu  = s * (1.0f / N_);
        float var = fmaxf(s2 * (1.0f / N_) - mu * mu, 0.f);
        float sc  = gamma[h0 + tid] * rsqrtf(var + EPS_);
        prm[tid] = make_float2(sc, beta[h0 + tid] - mu * sc);
    }
    __syncthreads();

    unsigned short* ab = actT + (long)b * actStride;
#pragma unroll
    for (int mt = 0; mt < 4; ++mt) {
#pragma unroll
        for (int r4 = 0; r4 < 4; ++r4) {
            int row = mt * 16 + lq * 4 + r4;
            float2 p = prm[row];
#pragma unroll
            for (int nt = 0; nt < 4; ++nt) {
                float y = fmaxf(acc[mt][nt][r4] * p.x + p.y, 0.f);
                unsigned short hv = f2bf(y);
                long idx = (long)(h0 + row) * N_ + wn + nt * 16 + lr;
                ab[idx] = hv;
                ab[actLo + idx] = f2bf(y - bf2f(hv));
            }
        }
    }
}

// ---- comb = h + hs : read actT hi/lo [H,N], transpose, add h, fp32 [N,H] -
__global__ __launch_bounds__(256) void comb_transpose_kernel(
    const unsigned short* __restrict__ actT, long actStride, long actLo,
    const float* __restrict__ h, float* __restrict__ comb)
{
    int b  = blockIdx.z;
    int n0 = blockIdx.x * 64, h0 = blockIdx.y * 64;
    __shared__ float tile[64][65];
    const unsigned short* ab = actT + (long)b * actStride;
    int x = threadIdx.x & 63, y0 = threadIdx.x >> 6;
#pragma unroll
    for (int i = 0; i < 16; ++i) {
        int y = y0 * 16 + i;                         // h-local
        long idx = (long)(h0 + y) * N_ + n0 + x;
        tile[y][x] = bf2f(ab[idx]) + bf2f(ab[actLo + idx]);
    }
    __syncthreads();
#pragma unroll
    for (int i = 0; i < 16; ++i) {
        int y = y0 * 16 + i;                         // n-local
        long o = ((long)b * N_ + n0 + y) * H_ + h0 + x;
        comb[o] = h[o] + tile[x][y];
    }
}

// -------------------- fp32 tiled GEMM (decoder only) ----------------------
__global__ __launch_bounds__(256) void gemm_kernel(
    const float* __restrict__ A, long aStride,
    const float* __restrict__ Bm, long bStride,
    float* __restrict__ C, long cStride,
    int M, int Nn, int K,
    const float* __restrict__ bias)
{
    int b  = blockIdx.z;
    int m0 = blockIdx.y * TILE;
    int n0 = blockIdx.x * TILE;
    const float* Ab  = A + (long)b * aStride;
    const float* Bb  = Bm + (long)b * bStride;
    float*       Cb  = C + (long)b * cStride;

    __shared__ float As[KC][TILE];
    __shared__ float Bs[KC][TILE];

    int tid = threadIdx.x;
    int tx  = tid & 15;
    int ty  = tid >> 4;
    int tx4 = tx << 2;
    int ty4 = ty << 2;
    int lr  = tid >> 2;
    int lc4 = (tid & 3) << 2;
    int br  = tid >> 4;
    int bc4 = (tid & 15) << 2;

    float acc[4][4] = {};

    for (int k0 = 0; k0 < K; k0 += KC) {
        float4 av = *(const float4*)(Ab + (long)(m0 + lr) * K + k0 + lc4);
        As[lc4 + 0][lr] = av.x;
        As[lc4 + 1][lr] = av.y;
        As[lc4 + 2][lr] = av.z;
        As[lc4 + 3][lr] = av.w;
        int cc = n0 + bc4;
        float4 bv = make_float4(0.f, 0.f, 0.f, 0.f);
        const float* bp = Bb + (long)(k0 + br) * Nn + cc;
        if (cc + 3 < Nn) {
            bv = *(const float4*)bp;
        } else {
            if (cc + 0 < Nn) bv.x = bp[0];
            if (cc + 1 < Nn) bv.y = bp[1];
            if (cc + 2 < Nn) bv.z = bp[2];
            if (cc + 3 < Nn) bv.w = bp[3];
        }
        *(float4*)&Bs[br][bc4] = bv;
        __syncthreads();
#pragma unroll
        for (int kk = 0; kk < KC; ++kk) {
            float4 a  = *(const float4*)&As[kk][ty4];
            float4 bq = *(const float4*)&Bs[kk][tx4];
            acc[0][0] += a.x * bq.x; acc[0][1] += a.x * bq.y;
            acc[0][2] += a.x * bq.z; acc[0][3] += a.x * bq.w;
            acc[1][0] += a.y * bq.x; acc[1][1] += a.y * bq.y;
            acc[1][2] += a.y * bq.z; acc[1][3] += a.y * bq.w;
            acc[2][0] += a.z * bq.x; acc[2][1] += a.z * bq.y;
            acc[2][2] += a.z * bq.z; acc[2][3] += a.z * bq.w;
            acc[3][0] += a.w * bq.x; acc[3][1] += a.w * bq.y;
            acc[3][2] += a.w * bq.z; acc[3][3] += a.w * bq.w;
        }
        __syncthreads();
    }

#pragma unroll
    for (int i = 0; i < 4; ++i) {
        int r = m0 + ty4 + i;
#pragma unroll
        for (int j = 0; j < 4; ++j) {
            int c = n0 + tx4 + j;
            if (c < Nn) {
                Cb[(long)r * Nn + c] = acc[i][j] + (bias ? bias[c] : 0.f);
            }
        }
    }
}

// --------------------------------------------------------------------------
extern "C" void kernel_launch(void* const* d_in, const int* in_sizes, int n_in,
                              void* d_out, int out_size, void* d_ws, size_t ws_size,
                              hipStream_t stream) {
    const float* obs    = (const float*)d_in[0];
    const int*   hyper  = (const int*)d_in[1];
    const float* Wenc   = (const float*)d_in[2];
    const float* benc   = (const float*)d_in[3];
    const float* thetas = (const float*)d_in[4];
    const float* convb  = (const float*)d_in[5];
    const float* gammas = (const float*)d_in[6];
    const float* betas  = (const float*)d_in[7];
    const float* Wdec   = (const float*)d_in[8];
    const float* bdec   = (const float*)d_in[9];
    float* out = (float*)d_out;

    char* w = (char*)d_ws;
    auto alloc = [&](size_t bytes) { char* p = w; w += (bytes + 255) & ~255ULL; return p; };
    float* h     = (float*)alloc((size_t)B_ * N_ * H_ * 4);
    float* comb  = (float*)alloc((size_t)B_ * N_ * H_ * 4);
    float* DinvN = (float*)alloc((size_t)B_ * N_ * 4);
    float* BinvM = (float*)alloc((size_t)B_ * M_ * 4);
    unsigned short* Hmat  = (unsigned short*)alloc((size_t)B_ * N_ * M_ * 2);
    unsigned short* HmatT = (unsigned short*)alloc((size_t)B_ * M_ * N_ * 2);
    unsigned short* actT  = (unsigned short*)alloc((size_t)B_ * H_ * N_ * 2 * 2); // hi+lo
    unsigned short* Z     = (unsigned short*)alloc((size_t)B_ * M_ * H_ * 2 * 2);
    unsigned short* WtT   = (unsigned short*)alloc((size_t)B_ * H_ * M_ * 2 * 2);
    unsigned short* thT   = (unsigned short*)alloc((size_t)L_ * H_ * H_ * 2 * 2);

    const long actLo = (long)B_ * H_ * N_;
    const long zLo   = (long)B_ * M_ * H_;
    const long wtLo  = (long)B_ * H_ * M_;
    const long thLo  = (long)L_ * H_ * H_;

    hipMemsetAsync(BinvM, 0, (size_t)B_ * M_ * 4, stream);
    encoder_kernel<<<B_ * N_, 256, 0, stream>>>(obs, Wenc, benc, h);
    build_kernel<<<dim3(B_, 8), 256, 0, stream>>>(hyper, Hmat, HmatT, DinvN, BinvM);
    inv_kernel<<<(B_ * M_ + 255) / 256, 256, 0, stream>>>(BinvM, B_ * M_);
    transpose_f32_bf16split<<<dim3(4, 4, 3), 256, 0, stream>>>(
        thetas, (long)H_ * H_, thT, (long)H_ * H_, thLo, H_, H_);
    // actT = h^T split bf16 (consumed by layer-0 gemm1 before being rewritten)
    transpose_f32_bf16split<<<dim3(4, 8, B_), 256, 0, stream>>>(
        h, (long)N_ * H_, actT, (long)H_ * N_, actLo, N_, H_);

    for (int l = 0; l < L_; ++l) {
        // Z = Binv * (HmatT @ act)  [128,256], K=512 ; A exact, B split
        mfma_gemm<1, 2, false, true, true><<<dim3(2, 2, B_), 128, 0, stream>>>(
            HmatT, (long)M_ * N_, 0, actT, (long)H_ * N_, actLo,
            Z, (long)M_ * H_, zLo, M_, H_, N_, BinvM, M_, nullptr);
        // WtT = thetaT_l @ Z^T  [256,128], K=256 ; both split
        mfma_gemm<1, 2, true, true, true><<<dim3(1, 4, B_), 128, 0, stream>>>(
            thT + (size_t)l * H_ * H_, 0, thLo, Z, (long)M_ * H_, zLo,
            WtT, (long)H_ * M_, wtLo, H_, M_, H_, nullptr, 0, nullptr);
        // fused: hcT = Dinv*(WtT @ Hmat^T) + convb ; BN over n ; ReLU ; actT
        gemm3_bn_kernel<<<dim3(1, 4, B_), 512, 0, stream>>>(
            WtT, (long)H_ * M_, wtLo, Hmat, (long)N_ * M_,
            DinvN, convb + (size_t)l * H_,
            gammas + (size_t)l * H_, betas + (size_t)l * H_,
            actT, (long)H_ * N_, actLo);
    }
    // comb = h + h_social (transpose actT back to [N,H], fp32)
    comb_transpose_kernel<<<dim3(8, 4, B_), 256, 0, stream>>>(
        actT, (long)H_ * N_, actLo, h, comb);
    // out = comb @ Wdec + bdec (fp32)
    gemm_kernel<<<dim3(1, N_ / TILE, B_), 256, 0, stream>>>(
        comb, (long)N_ * H_, Wdec, 0,
        out, (long)N_ * P2_, N_, P2_, H_, bdec);
}